// Round 18
// baseline (263.186 us; speedup 1.0000x reference)
//
#include <hip/hip_runtime.h>
#include <stdint.h>

#define HW   1369      // 37*37 output pixels
#define QW   39        // padded row width
#define QP2  1648      // padded plane rows per (b) in Xp (1616 used + panel slack)
#define QT   1536      // q rows in x1 (per batch)
#define CIN  1024
#define CMID 512
#define KTOT 9216      // 9 * 1024
#define NTIL 144       // K-tiles: 16 cblocks(64) * 9 taps, cblock-major tap-inner
#define PANEL 18432    // A panel: 288 rows x 64 el = 36 KB (single-buffered)
#define BSL  8192      // B slot stride (elements): 128 x 64 (16 KB), double-buffered

typedef float  f32x4   __attribute__((ext_vector_type(4)));
typedef float  f32x16  __attribute__((ext_vector_type(16)));
typedef __bf16 bf16x8  __attribute__((ext_vector_type(8)));

__device__ __forceinline__ uint16_t f2bf(float f) {
  uint32_t u = __float_as_uint(f);
  u += 0x7fffu + ((u >> 16) & 1u);
  return (uint16_t)(u >> 16);
}

__device__ __forceinline__ uint32_t f2bf2(float lo, float hi) {
  return (uint32_t)f2bf(lo) | ((uint32_t)f2bf(hi) << 16);
}

// global -> LDS direct copy, 16B per lane. LDS dest = wave-uniform base + lane*16.
__device__ __forceinline__ void gll16(const void* g, void* l) {
  const __attribute__((address_space(1))) uint32_t* ga =
      (const __attribute__((address_space(1))) uint32_t*)(uintptr_t)g;
  __attribute__((address_space(3))) uint32_t* la =
      (__attribute__((address_space(3))) uint32_t*)(uint32_t)(uintptr_t)l;
  __builtin_amdgcn_global_load_lds(ga, la, 16, 0, 0);
}

// ---------- prep: zero ONLY the border rows of Xp (pad kernel writes interior) ----------
__global__ void k_zero_border(uint16_t* __restrict__ Xp) {
  const int bx = blockIdx.x;                 // 16 * 210
  const int batch = bx / 210, idx = bx - batch * 210;
  int q;
  if (idx < 40)       q = idx;
  else if (idx < 136) q = 1520 + (idx - 40);
  else {
    const int k = idx - 136;
    const int pair = k >> 1;
    q = (k & 1) ? ((pair + 1) * 39 + 38) : ((pair + 2) * 39);
  }
  uint64_t* p = (uint64_t*)(Xp + ((size_t)batch * QP2 + q) * CIN);
  p[threadIdx.x] = 0ull;
}

// ---------- prep: fmap [b][c][h][w] f32 -> Xp [b][q][c] bf16, vectorized stores ----------
__global__ void k_pad_transpose(const float* __restrict__ fmap, uint16_t* __restrict__ Xp) {
  __shared__ float t[64][33];
  const int b = blockIdx.z;
  const int c0 = blockIdx.y * 64;
  const int p0 = blockIdx.x * 32;
  const int tx = threadIdx.x, ty = threadIdx.y;   // 32 x 8
  const float* src = fmap + ((size_t)b * CIN + c0) * HW + p0;
  const bool pin = (p0 + tx) < HW;
#pragma unroll
  for (int i = 0; i < 8; ++i) {
    int cc = ty * 8 + i;
    t[cc][tx] = pin ? src[(size_t)cc * HW + tx] : 0.f;
  }
  __syncthreads();
#pragma unroll
  for (int i = 0; i < 4; ++i) {
    int pl = ty + i * 8;
    int p = p0 + pl;
    if (p < HW) {
      int h = p / 37, w = p - h * 37;
      int q = (h + 1) * QW + (w + 1);
      uint32_t* dst = (uint32_t*)(Xp + ((size_t)b * QP2 + q) * CIN + c0);
      dst[tx] = f2bf2(t[2 * tx][pl], t[2 * tx + 1][pl]);
    }
  }
}

// ---------- prep: W1 [o][c][3][3] f32 -> Apk [o][r*1024+c] bf16, uint32 stores ----------
__global__ void k_pack_w1(const float* __restrict__ W1, uint16_t* __restrict__ Apk) {
  int pid = blockIdx.x * 256 + threadIdx.x;
  if (pid >= 512 * (KTOT / 2)) return;
  int o = pid / (KTOT / 2), k2 = pid - o * (KTOT / 2);
  int k = k2 * 2;
  int r = k >> 10, c = k & 1023;
  const float* wb = W1 + ((size_t)o * CIN + c) * 9 + r;
  ((uint32_t*)Apk)[pid] = f2bf2(wb[0], wb[9]);
}

// ---------- prep: W2 [120][512] f32 -> W2p [128][512] bf16 ----------
__global__ void k_pack_w2(const float* __restrict__ W2, uint16_t* __restrict__ W2p) {
  int idx = blockIdx.x * 256 + threadIdx.x;
  int j = idx >> 9, o = idx & 511;
  W2p[idx] = (j < 120) ? f2bf(W2[j * 512 + o]) : (uint16_t)0;
}

// ---------- conv1: r16 structure, MFMA shape 32x32x16 (15% faster matrix pipe) ----------
// Block 192x128, 4 waves 2M x 2N (wave 96x64 = 3x2 tiles of 32x32), 2 blocks/CU.
// A panel (288x64, staged once per 9-tile group) + B double-buffered slots, one
// vmcnt(0)+barrier per tile -- all unchanged from r16 (187us baseline).
// Per tile: 4 k-steps of K=16; same 20 ds_read_b128, but 24 MFMAs @4061 FLOP/cyc
// instead of 48 @3378 (m119). C/D: col=lane&31, row=(reg&3)+8*(reg>>2)+4*(lane>>5).
// A/B frags: row=lane&31, k=(lane>>5)*8+e (blocked pattern, contiguous bf16x8).
__global__ __launch_bounds__(256, 2) void k_conv1(
    const uint16_t* __restrict__ Xp, const uint16_t* __restrict__ Apk,
    const float* __restrict__ b1, uint16_t* __restrict__ x1) {
  __shared__ __align__(16) uint16_t lds[PANEL + 2 * BSL];   // 69632 B

  const int tid  = threadIdx.x;
  const int wid  = tid >> 6, lane = tid & 63;
  const int l31  = lane & 31, kg16 = (lane >> 5) * 16;   // k-group byte offset
  const int wm   = wid >> 1,  wn = wid & 1;              // 2M x 2N

  const int bid = blockIdx.x;
  const int g   = (bid & 7) * 64 + (bid >> 3);
  const int mt_ = g >> 2, nt = g & 3;
  const int batch = mt_ >> 3, qb = (mt_ & 7) * 192;
  const int o0 = nt * 128;
  const uint16_t* Xb = Xp + (size_t)batch * QP2 * CIN;

  // B staging (r11 mapping): srow = tid>>3 (0..31), pre-swizzled source col
  const int scol = ((tid & 7) ^ ((tid >> 3) & 7)) * 8;
  const int srow = tid >> 3;

  // panel staging: per call each wave writes 8 rows (1KB); row&7 = sR8
  const int sR8 = lane >> 3;
  const int sc8 = ((lane & 7) ^ sR8) * 8;

  // B fragment row parity (B rows: (wn*64 + ntile*32 + l31)&7 = lane&7)
  const int r7b = lane & 7;

  f32x16 acc[3][2] = {};

#define STPAN(cb1, call) do {                                                         \
    if ((cb1) < 16) {                                                                 \
      const int c0_ = (cb1) << 6;                                                     \
      const int Rb  = (call) * 32 + wid * 8;                                          \
      gll16(Xb + (size_t)(qb + Rb + sR8) * CIN + c0_ + sc8, lds + Rb * 64);           \
    }                                                                                 \
  } while (0)

#define STAGEB(cbv, tapv, slot) do {                                                  \
    const int c0_ = (cbv) << 6;                                                       \
    uint16_t* sb = lds + PANEL + (slot) * BSL;                                        \
    _Pragma("unroll")                                                                 \
    for (int j = 0; j < 4; ++j)                                                       \
      gll16(Apk + (size_t)(o0 + j * 32 + srow) * KTOT + ((tapv) << 10) + c0_ + scol,  \
            sb + (j * 256 + wid * 64) * 8);                                           \
  } while (0)

#pragma unroll
  for (int c = 0; c < 9; ++c) STPAN(0, c);
  STAGEB(0, 0, 0);

  for (int cb = 0; cb < 16; ++cb) {
#pragma unroll
    for (int tap = 0; tap < 9; ++tap) {
      const int t = cb * 9 + tap;
      asm volatile("s_waitcnt vmcnt(0)" ::: "memory");
      asm volatile("s_barrier" ::: "memory");
      __builtin_amdgcn_sched_barrier(0);
      if (tap < 8)           STAGEB(cb, tap + 1, (t + 1) & 1);
      else if (cb + 1 < 16)  STAGEB(cb + 1, 0, (t + 1) & 1);

      const int off_ = (tap / 3) * QW + tap % 3;
      const int r7a  = (off_ + l31) & 7;           // A row parity (wm*96, mt*32 = 0 mod 8)
      const uint16_t* Bs = lds + PANEL + (t & 1) * BSL;

      bf16x8 av[3][4], bv[2][4];
#pragma unroll
      for (int ks = 0; ks < 4; ++ks) {
        const int cea = ((ks * 32 + kg16) ^ (r7a << 4)) >> 1;   // element col (swizzled)
        const int ceb = ((ks * 32 + kg16) ^ (r7b << 4)) >> 1;
#pragma unroll
        for (int mt = 0; mt < 3; ++mt)
          av[mt][ks] = *(const bf16x8*)(lds + (off_ + wm * 96 + mt * 32 + l31) * 64 + cea);
#pragma unroll
        for (int nb = 0; nb < 2; ++nb)
          bv[nb][ks] = *(const bf16x8*)(Bs + (wn * 64 + nb * 32 + l31) * 64 + ceb);
      }
      __builtin_amdgcn_s_setprio(1);
#pragma unroll
      for (int ks = 0; ks < 4; ++ks)
#pragma unroll
        for (int mt = 0; mt < 3; ++mt)
#pragma unroll
          for (int nb = 0; nb < 2; ++nb)
            acc[mt][nb] = __builtin_amdgcn_mfma_f32_32x32x16_bf16(
                av[mt][ks], bv[nb][ks], acc[mt][nb], 0, 0, 0);
      __builtin_amdgcn_s_setprio(0);

      if (tap == 8) {
        asm volatile("s_barrier" ::: "memory");
        __builtin_amdgcn_sched_barrier(0);
        if (cb + 1 < 16) {
#pragma unroll
          for (int c = 0; c < 9; ++c) STPAN(cb + 1, c);
        }
      }
    }
  }

  // epilogue: bias + ReLU6 -> x1 bf16.
  // D layout (32x32): col o = lane&31, row q-offset = (reg&3) + 8*(reg>>2) + 4*(lane>>5)
  const int qg = (lane >> 5) * 4;
#pragma unroll
  for (int nb = 0; nb < 2; ++nb) {
    const int o = o0 + wn * 64 + nb * 32 + l31;
    const float bias = b1[o];
#pragma unroll
    for (int mt = 0; mt < 3; ++mt) {
#pragma unroll
      for (int reg = 0; reg < 16; ++reg) {
        const int q = qb + wm * 96 + mt * 32 + (reg & 3) + 8 * (reg >> 2) + qg;
        float x = acc[mt][nb][reg] + bias;
        x = fminf(fmaxf(x, 0.f), 6.f);
        x1[((size_t)batch * QT + q) * CMID + o] = f2bf(x);
      }
    }
  }
#undef STAGEB
#undef STPAN
}

// ---------- conv2: out[b][h][w][j] = sum_o x1[q][o] * W2[j][o] + b2[j] ----------
__global__ __launch_bounds__(256, 2) void k_conv2(
    const uint16_t* __restrict__ x1, const uint16_t* __restrict__ W2p,
    const float* __restrict__ b2, float* __restrict__ out) {
  __shared__ __align__(16) uint16_t lA[64 * 64];
  __shared__ __align__(16) uint16_t lB[128 * 64];
  const int tid = threadIdx.x;
  const int wid = tid >> 6, lane = tid & 63;
  const int b = blockIdx.z, q0 = blockIdx.x * 64;
  const uint16_t* Ab = x1 + (size_t)b * QT * CMID;
  const int wm = wid >> 1, wn = wid & 1;
  const int lrow = lane & 15, lk = (lane >> 4) * 8;
  f32x4 acc[2][4] = {};

  for (int kt = 0; kt < 8; ++kt) {
    const int c0 = kt << 6;
#pragma unroll
    for (int i = 0; i < 2; ++i) {
      int wb = i * 256 + wid * 64;
      int chunk = wb + lane;
      int row = chunk >> 3, ch = chunk & 7;
      gll16(Ab + (size_t)(q0 + row) * CMID + c0 + ch * 8, lA + wb * 8);
    }
#pragma unroll
    for (int i = 0; i < 4; ++i) {
      int wb = i * 256 + wid * 64;
      int chunk = wb + lane;
      int row = chunk >> 3, ch = chunk & 7;
      gll16(W2p + (size_t)row * CMID + c0 + ch * 8, lB + wb * 8);
    }
    __syncthreads();
#pragma unroll
    for (int kk = 0; kk < 2; ++kk) {
      bf16x8 av[2], bv[4];
#pragma unroll
      for (int mi = 0; mi < 2; ++mi)
        av[mi] = *(const bf16x8*)(lA + (wm * 32 + mi * 16 + lrow) * 64 + kk * 32 + lk);
#pragma unroll
      for (int ni = 0; ni < 4; ++ni)
        bv[ni] = *(const bf16x8*)(lB + (wn * 64 + ni * 16 + lrow) * 64 + kk * 32 + lk);
#pragma unroll
      for (int mi = 0; mi < 2; ++mi)
#pragma unroll
        for (int ni = 0; ni < 4; ++ni)
          acc[mi][ni] = __builtin_amdgcn_mfma_f32_16x16x32_bf16(av[mi], bv[ni], acc[mi][ni], 0, 0, 0);
    }
    __syncthreads();
  }

  const int qr = (lane >> 4) * 4;
#pragma unroll
  for (int ni = 0; ni < 4; ++ni) {
    int j = wn * 64 + ni * 16 + lrow;
    if (j < 120) {
      float bias = b2[j];
#pragma unroll
      for (int mi = 0; mi < 2; ++mi) {
#pragma unroll
        for (int v = 0; v < 4; ++v) {
          int q = q0 + wm * 32 + mi * 16 + qr + v;
          int h = q / QW, w = q - h * QW;
          if (h < 37 && w < 37) {
            out[((size_t)b * HW + h * 37 + w) * 120 + j] = acc[mi][ni][v] + bias;
          }
        }
      }
    }
  }
}

extern "C" void kernel_launch(void* const* d_in, const int* in_sizes, int n_in,
                              void* d_out, int out_size, void* d_ws, size_t ws_size,
                              hipStream_t stream) {
  const float* fmap = (const float*)d_in[0];
  const float* W1   = (const float*)d_in[1];
  const float* b1   = (const float*)d_in[2];
  const float* W2   = (const float*)d_in[3];
  const float* b2   = (const float*)d_in[4];
  float* out = (float*)d_out;

  uint8_t* ws = (uint8_t*)d_ws;
  const size_t XP_BYTES  = (size_t)16 * QP2 * CIN * 2;  // 54,001,664
  const size_t W1P_BYTES = (size_t)512 * KTOT * 2;      //  9,437,184
  const size_t W2P_BYTES = (size_t)128 * 512 * 2;       //    131,072
  uint16_t* Xp  = (uint16_t*)ws;
  uint16_t* Apk = (uint16_t*)(ws + XP_BYTES);
  uint16_t* W2p = (uint16_t*)(ws + XP_BYTES + W1P_BYTES);
  uint16_t* x1  = (uint16_t*)(ws + XP_BYTES + W1P_BYTES + W2P_BYTES);

  k_zero_border<<<dim3(16 * 210), dim3(256), 0, stream>>>(Xp);
  k_pad_transpose<<<dim3(43, 16, 16), dim3(32, 8), 0, stream>>>(fmap, Xp);
  k_pack_w1<<<dim3((512 * (KTOT / 2) + 255) / 256), dim3(256), 0, stream>>>(W1, Apk);
  k_pack_w2<<<dim3(256), dim3(256), 0, stream>>>(W2, W2p);
  k_conv1<<<dim3(512), dim3(256), 0, stream>>>(Xp, Apk, b1, x1);
  k_conv2<<<dim3(24, 1, 16), dim3(256), 0, stream>>>(x1, W2p, b2, out);
}

// Round 19
// 230.672 us; speedup vs baseline: 1.1410x; 1.1410x over previous
//
#include <hip/hip_runtime.h>
#include <stdint.h>

#define HW   1369      // 37*37 output pixels
#define QW   39        // padded row width
#define QP2  1648      // padded plane rows per (b) in Xp (1616 used + panel slack)
#define QT   1536      // q rows in x1 (per batch)
#define CIN  1024
#define CMID 512
#define KTOT 9216      // 9 * 1024
#define NTIL 144       // K-tiles: 16 cblocks(64) * 9 taps, cblock-major tap-inner
#define PANEL 18432    // A panel: 288 rows x 64 el = 36 KB (single-buffered)
#define BSL  8192      // B slot stride (elements): 128 x 64 (16 KB), double-buffered

typedef float  f32x4  __attribute__((ext_vector_type(4)));
typedef __bf16 bf16x8 __attribute__((ext_vector_type(8)));

__device__ __forceinline__ uint16_t f2bf(float f) {
  uint32_t u = __float_as_uint(f);
  u += 0x7fffu + ((u >> 16) & 1u);
  return (uint16_t)(u >> 16);
}

// global -> LDS direct copy, 16B per lane. LDS dest = wave-uniform base + lane*16.
__device__ __forceinline__ void gll16(const void* g, void* l) {
  const __attribute__((address_space(1))) uint32_t* ga =
      (const __attribute__((address_space(1))) uint32_t*)(uintptr_t)g;
  __attribute__((address_space(3))) uint32_t* la =
      (__attribute__((address_space(3))) uint32_t*)(uint32_t)(uintptr_t)l;
  __builtin_amdgcn_global_load_lds(ga, la, 16, 0, 0);
}

// ---------- prep: zero ONLY the border rows of Xp (pad kernel writes interior) ----------
__global__ void k_zero_border(uint16_t* __restrict__ Xp) {
  const int bx = blockIdx.x;                 // 16 * 210
  const int batch = bx / 210, idx = bx - batch * 210;
  int q;
  if (idx < 40)       q = idx;
  else if (idx < 136) q = 1520 + (idx - 40);
  else {
    const int k = idx - 136;
    const int pair = k >> 1;
    q = (k & 1) ? ((pair + 1) * 39 + 38) : ((pair + 2) * 39);
  }
  uint64_t* p = (uint64_t*)(Xp + ((size_t)batch * QP2 + q) * CIN);
  p[threadIdx.x] = 0ull;
}

// ---------- prep: fmap [b][c][h][w] f32 -> Xp [b][q][c] bf16 (interior rows) ----------
__global__ void k_pad_transpose(const float* __restrict__ fmap, uint16_t* __restrict__ Xp) {
  __shared__ float t[32][33];
  const int b = blockIdx.z;
  const int c0 = blockIdx.y * 32;
  const int p0 = blockIdx.x * 32;
  const int tx = threadIdx.x, ty = threadIdx.y;
  const float* src = fmap + ((size_t)b * CIN + c0) * HW + p0;
#pragma unroll
  for (int i = 0; i < 4; ++i) {
    int cc = ty + i * 8;
    t[cc][tx] = (p0 + tx < HW) ? src[(size_t)cc * HW + tx] : 0.f;
  }
  __syncthreads();
#pragma unroll
  for (int i = 0; i < 4; ++i) {
    int pl = ty + i * 8;
    int p = p0 + pl;
    if (p < HW) {
      int h = p / 37, w = p - h * 37;
      int q = (h + 1) * QW + (w + 1);
      Xp[((size_t)b * QP2 + q) * CIN + c0 + tx] = f2bf(t[tx][pl]);
    }
  }
}

// ---------- prep: W1 [o][c][3][3] f32 -> Apk [o][r*1024+c] bf16 ----------
__global__ void k_pack_w1(const float* __restrict__ W1, uint16_t* __restrict__ Apk) {
  int idx = blockIdx.x * 256 + threadIdx.x;
  if (idx >= 512 * KTOT) return;
  int o = idx / KTOT, k = idx - o * KTOT;
  int r = k >> 10, c = k & 1023;
  Apk[idx] = f2bf(W1[((size_t)o * CIN + c) * 9 + r]);
}

// ---------- prep: W2 [120][512] f32 -> W2p [128][512] bf16 ----------
__global__ void k_pack_w2(const float* __restrict__ W2, uint16_t* __restrict__ W2p) {
  int idx = blockIdx.x * 256 + threadIdx.x;
  int j = idx >> 9, o = idx & 511;
  W2p[idx] = (j < 120) ? f2bf(W2[j * 512 + o]) : (uint16_t)0;
}

// ---------- conv1: r11 structure + tap-reuse A panel (FROZEN: 187us / 60% util) ----------
// Block 192x128, 4 waves 2M x 2N (wave 96x64), grid 512 = 2 blocks/CU.
// 16x16x32 MFMA (32x32x16 regressed: 4-way LDS conflict, r18). A panel 288x64
// staged once per 9-tile group; B double-buffered; one vmcnt(0)+barrier/tile.
__global__ __launch_bounds__(256, 2) void k_conv1(
    const uint16_t* __restrict__ Xp, const uint16_t* __restrict__ Apk,
    const float* __restrict__ b1, uint16_t* __restrict__ x1) {
  __shared__ __align__(16) uint16_t lds[PANEL + 2 * BSL];   // 69632 B

  const int tid  = threadIdx.x;
  const int wid  = tid >> 6, lane = tid & 63;
  const int lrow = lane & 15, lq = lane >> 4;
  const int wm   = wid >> 1,  wn = wid & 1;           // 2M x 2N

  const int bid = blockIdx.x;
  const int g   = (bid & 7) * 64 + (bid >> 3);
  const int mt  = g >> 2, nt = g & 3;
  const int batch = mt >> 3, qb = (mt & 7) * 192;
  const int o0 = nt * 128;
  const uint16_t* Xb = Xp + (size_t)batch * QP2 * CIN;

  const int xorb    = (lrow & 7) << 4;
  const int col_el0 = ((lq * 16) ^ xorb) >> 1;
  const int col_el1 = col_el0 ^ 32;

  const int scol = ((tid & 7) ^ ((tid >> 3) & 7)) * 8;
  const int srow = tid >> 3;

  const int sR8 = lane >> 3;
  const int sc8 = ((lane & 7) ^ sR8) * 8;

  f32x4 acc[6][4] = {};

#define STPAN(cb1, call) do {                                                         \
    if ((cb1) < 16) {                                                                 \
      const int c0_ = (cb1) << 6;                                                     \
      const int Rb  = (call) * 32 + wid * 8;                                          \
      gll16(Xb + (size_t)(qb + Rb + sR8) * CIN + c0_ + sc8, lds + Rb * 64);           \
    }                                                                                 \
  } while (0)

#define STAGEB(cbv, tapv, slot) do {                                                  \
    const int c0_ = (cbv) << 6;                                                       \
    uint16_t* sb = lds + PANEL + (slot) * BSL;                                        \
    _Pragma("unroll")                                                                 \
    for (int j = 0; j < 4; ++j)                                                       \
      gll16(Apk + (size_t)(o0 + j * 32 + srow) * KTOT + ((tapv) << 10) + c0_ + scol,  \
            sb + (j * 256 + wid * 64) * 8);                                           \
  } while (0)

#pragma unroll
  for (int c = 0; c < 9; ++c) STPAN(0, c);
  STAGEB(0, 0, 0);

  for (int cb = 0; cb < 16; ++cb) {
#pragma unroll
    for (int tap = 0; tap < 9; ++tap) {
      const int t = cb * 9 + tap;
      asm volatile("s_waitcnt vmcnt(0)" ::: "memory");
      asm volatile("s_barrier" ::: "memory");
      __builtin_amdgcn_sched_barrier(0);
      if (tap < 8)           STAGEB(cb, tap + 1, (t + 1) & 1);
      else if (cb + 1 < 16)  STAGEB(cb + 1, 0, (t + 1) & 1);

      const int off_ = (tap / 3) * QW + tap % 3;
      const int r7   = (off_ + lrow) & 7;
      const int ce0  = ((lq * 16) ^ (r7 << 4)) >> 1;
      const int ce1  = ce0 ^ 32;
      const uint16_t* Bs = lds + PANEL + (t & 1) * BSL;

      bf16x8 av0[6], av1[6], bv0[4], bv1[4];
#pragma unroll
      for (int n = 0; n < 4; ++n) {
        const uint16_t* br = Bs + (wn * 64 + n * 16 + lrow) * 64;
        bv0[n] = *(const bf16x8*)(br + col_el0);
        bv1[n] = *(const bf16x8*)(br + col_el1);
      }
#pragma unroll
      for (int m = 0; m < 6; ++m) {
        const uint16_t* ar = lds + (off_ + wm * 96 + m * 16 + lrow) * 64;
        av0[m] = *(const bf16x8*)(ar + ce0);
        av1[m] = *(const bf16x8*)(ar + ce1);
      }
      __builtin_amdgcn_s_setprio(1);
#pragma unroll
      for (int m = 0; m < 6; ++m)
#pragma unroll
        for (int n = 0; n < 4; ++n)
          acc[m][n] = __builtin_amdgcn_mfma_f32_16x16x32_bf16(av0[m], bv0[n], acc[m][n], 0, 0, 0);
#pragma unroll
      for (int m = 0; m < 6; ++m)
#pragma unroll
        for (int n = 0; n < 4; ++n)
          acc[m][n] = __builtin_amdgcn_mfma_f32_16x16x32_bf16(av1[m], bv1[n], acc[m][n], 0, 0, 0);
      __builtin_amdgcn_s_setprio(0);

      if (tap == 8) {
        asm volatile("s_barrier" ::: "memory");
        __builtin_amdgcn_sched_barrier(0);
        if (cb + 1 < 16) {
#pragma unroll
          for (int c = 0; c < 9; ++c) STPAN(cb + 1, c);
        }
      }
    }
  }

  // epilogue: bias + ReLU6 -> x1 bf16
  const int qr = lq * 4;
#pragma unroll
  for (int n = 0; n < 4; ++n) {
    const int o = o0 + wn * 64 + n * 16 + lrow;
    const float bias = b1[o];
#pragma unroll
    for (int m = 0; m < 6; ++m) {
#pragma unroll
      for (int v = 0; v < 4; ++v) {
        const int q = qb + wm * 96 + m * 16 + qr + v;
        float x = acc[m][n][v] + bias;
        x = fminf(fmaxf(x, 0.f), 6.f);
        x1[((size_t)batch * QT + q) * CMID + o] = f2bf(x);
      }
    }
  }
#undef STAGEB
#undef STPAN
}

// ---------- conv2: out[b][h][w][j] = sum_o x1[q][o] * W2[j][o] + b2[j] ----------
__global__ __launch_bounds__(256, 2) void k_conv2(
    const uint16_t* __restrict__ x1, const uint16_t* __restrict__ W2p,
    const float* __restrict__ b2, float* __restrict__ out) {
  __shared__ __align__(16) uint16_t lA[64 * 64];
  __shared__ __align__(16) uint16_t lB[128 * 64];
  const int tid = threadIdx.x;
  const int wid = tid >> 6, lane = tid & 63;
  const int b = blockIdx.z, q0 = blockIdx.x * 64;
  const uint16_t* Ab = x1 + (size_t)b * QT * CMID;
  const int wm = wid >> 1, wn = wid & 1;
  const int lrow = lane & 15, lk = (lane >> 4) * 8;
  f32x4 acc[2][4] = {};

  for (int kt = 0; kt < 8; ++kt) {
    const int c0 = kt << 6;
#pragma unroll
    for (int i = 0; i < 2; ++i) {
      int wb = i * 256 + wid * 64;
      int chunk = wb + lane;
      int row = chunk >> 3, ch = chunk & 7;
      gll16(Ab + (size_t)(q0 + row) * CMID + c0 + ch * 8, lA + wb * 8);
    }
#pragma unroll
    for (int i = 0; i < 4; ++i) {
      int wb = i * 256 + wid * 64;
      int chunk = wb + lane;
      int row = chunk >> 3, ch = chunk & 7;
      gll16(W2p + (size_t)row * CMID + c0 + ch * 8, lB + wb * 8);
    }
    __syncthreads();
#pragma unroll
    for (int kk = 0; kk < 2; ++kk) {
      bf16x8 av[2], bv[4];
#pragma unroll
      for (int mi = 0; mi < 2; ++mi)
        av[mi] = *(const bf16x8*)(lA + (wm * 32 + mi * 16 + lrow) * 64 + kk * 32 + lk);
#pragma unroll
      for (int ni = 0; ni < 4; ++ni)
        bv[ni] = *(const bf16x8*)(lB + (wn * 64 + ni * 16 + lrow) * 64 + kk * 32 + lk);
#pragma unroll
      for (int mi = 0; mi < 2; ++mi)
#pragma unroll
        for (int ni = 0; ni < 4; ++ni)
          acc[mi][ni] = __builtin_amdgcn_mfma_f32_16x16x32_bf16(av[mi], bv[ni], acc[mi][ni], 0, 0, 0);
    }
    __syncthreads();
  }

  const int qr = (lane >> 4) * 4;
#pragma unroll
  for (int ni = 0; ni < 4; ++ni) {
    int j = wn * 64 + ni * 16 + lrow;
    if (j < 120) {
      float bias = b2[j];
#pragma unroll
      for (int mi = 0; mi < 2; ++mi) {
#pragma unroll
        for (int v = 0; v < 4; ++v) {
          int q = q0 + wm * 32 + mi * 16 + qr + v;
          int h = q / QW, w = q - h * QW;
          if (h < 37 && w < 37) {
            out[((size_t)b * HW + h * 37 + w) * 120 + j] = acc[mi][ni][v] + bias;
          }
        }
      }
    }
  }
}

extern "C" void kernel_launch(void* const* d_in, const int* in_sizes, int n_in,
                              void* d_out, int out_size, void* d_ws, size_t ws_size,
                              hipStream_t stream) {
  const float* fmap = (const float*)d_in[0];
  const float* W1   = (const float*)d_in[1];
  const float* b1   = (const float*)d_in[2];
  const float* W2   = (const float*)d_in[3];
  const float* b2   = (const float*)d_in[4];
  float* out = (float*)d_out;

  uint8_t* ws = (uint8_t*)d_ws;
  const size_t XP_BYTES  = (size_t)16 * QP2 * CIN * 2;  // 54,001,664
  const size_t W1P_BYTES = (size_t)512 * KTOT * 2;      //  9,437,184
  const size_t W2P_BYTES = (size_t)128 * 512 * 2;       //    131,072
  uint16_t* Xp  = (uint16_t*)ws;
  uint16_t* Apk = (uint16_t*)(ws + XP_BYTES);
  uint16_t* W2p = (uint16_t*)(ws + XP_BYTES + W1P_BYTES);
  uint16_t* x1  = (uint16_t*)(ws + XP_BYTES + W1P_BYTES + W2P_BYTES);

  k_zero_border<<<dim3(16 * 210), dim3(256), 0, stream>>>(Xp);
  k_pad_transpose<<<dim3(43, 32, 16), dim3(32, 8), 0, stream>>>(fmap, Xp);
  k_pack_w1<<<dim3((512 * KTOT + 255) / 256), dim3(256), 0, stream>>>(W1, Apk);
  k_pack_w2<<<dim3(256), dim3(256), 0, stream>>>(W2, W2p);
  k_conv1<<<dim3(512), dim3(256), 0, stream>>>(Xp, Apk, b1, x1);
  k_conv2<<<dim3(24, 1, 16), dim3(256), 0, stream>>>(x1, W2p, b2, out);
}